// Round 2
// baseline (256.949 us; speedup 1.0000x reference)
//
#include <hip/hip_runtime.h>

#define B_ 16
#define L_ 1024
#define M_ 1024
#define H_ 128
#define NEGV -1e30f

typedef unsigned short u16;
typedef unsigned int u32;
typedef __bf16 bf16x8 __attribute__((ext_vector_type(8)));
typedef float f32x4 __attribute__((ext_vector_type(4)));

__device__ __forceinline__ u16 f2bf(float x){
  u32 u = __float_as_uint(x);
  u = (u + 0x7fffu + ((u >> 16) & 1u)) >> 16;
  return (u16)u;
}

// ---------------------------------------------------------------------------
// K0a/K0b: per-row dot product (t0 / s1m, f32 exact) + bf16 pre-convert
// (optionally scaled by mulw = text_modality_weight). One wave per row.
// ---------------------------------------------------------------------------
__global__ __launch_bounds__(256) void prep_rows(
    const float* __restrict__ src, const float* __restrict__ dotw,
    const float* __restrict__ mulw, u16* __restrict__ outbf,
    float* __restrict__ dotout, int nrows)
{
  int row = blockIdx.x * 4 + (threadIdx.x >> 6);
  int lane = threadIdx.x & 63;
  if (row >= nrows) return;
  const float* r = src + (size_t)row * H_;
  float2 x = *(const float2*)&r[lane * 2];
  float2 wv = *(const float2*)&dotw[lane * 2];
  float d = x.x * wv.x + x.y * wv.y;
  #pragma unroll
  for (int off = 32; off; off >>= 1) d += __shfl_xor(d, off);
  float2 mv = mulw ? *(const float2*)&mulw[lane * 2] : make_float2(1.f, 1.f);
  u32 packed = (u32)f2bf(x.x * mv.x) | ((u32)f2bf(x.y * mv.y) << 16);
  ((u32*)outbf)[(size_t)row * 64 + lane] = packed;
  if (lane == 0) dotout[row] = d;
}

// ---------------------------------------------------------------------------
// K0c: f32 (R=1024 x H=128) -> bf16 transposed (128 x 1024), per batch.
// blockIdx.z: low 4 bits = batch, bit 4 = which tensor (text / modality).
// ---------------------------------------------------------------------------
__global__ __launch_bounds__(256) void transpose_bf(
    const float* __restrict__ srcA, const float* __restrict__ srcB,
    u16* __restrict__ dstA, u16* __restrict__ dstB)
{
  int b = blockIdx.z & 15, sel = blockIdx.z >> 4;
  const float* src = (sel ? srcB : srcA) + (size_t)b * L_ * H_;
  u16* dst = (sel ? dstB : dstA) + (size_t)b * H_ * L_;
  int r0 = blockIdx.x * 64, h0 = blockIdx.y * 64;
  __shared__ u16 tile[64][65];
  int t = threadIdx.x;
  int j = t & 63, i0 = t >> 6;
  #pragma unroll
  for (int p = 0; p < 16; p++) {
    int i = i0 + p * 4;
    tile[i][j] = f2bf(src[(size_t)(r0 + i) * H_ + h0 + j]);
  }
  __syncthreads();
  int ii = (t & 15) * 4, jj0 = t >> 4;
  #pragma unroll
  for (int q = 0; q < 4; q++) {
    int jj = jj0 + q * 16;
    u32 lo = (u32)tile[ii][jj] | ((u32)tile[ii + 1][jj] << 16);
    u32 hi = (u32)tile[ii + 2][jj] | ((u32)tile[ii + 3][jj] << 16);
    uint2 pk; pk.x = lo; pk.y = hi;
    *(uint2*)&dst[(size_t)(h0 + jj) * L_ + r0 + ii] = pk;
  }
}

// ---------------------------------------------------------------------------
// Templated NT GEMM: D[i][j] = sum_k A[i][k] * Bm[j][k]  (both bf16 row-major,
// contiguous K). Tile: 64 (A-rows) x 128 (B-rows), BK=64, 4 waves (2x2),
// per-wave 32x64 = acc[2][4] 16x16 frags. XOR swizzle on 128B LDS rows.
// EPI: 0 = s-write (+t0+s1m+bias), 1 = out[text,a,text*a], 2 = cT bf16,
//      3 = out[text*b].
// ---------------------------------------------------------------------------
template<int EPI>
__global__ __launch_bounds__(256) void gemm_nt(
    const u16* __restrict__ A, const u16* __restrict__ Bm,
    int RA, int RB, int K,
    float* __restrict__ sout, const float* __restrict__ t0,
    const float* __restrict__ s1m, const float* __restrict__ bias,
    const float* __restrict__ text, float* __restrict__ out,
    u16* __restrict__ cT)
{
  int b = blockIdx.z;
  int a0 = blockIdx.x * 64, b0 = blockIdx.y * 128;
  int tid = threadIdx.x, lane = tid & 63, wid = tid >> 6;
  int wr = wid >> 1, wc = wid & 1;
  __shared__ __align__(16) char smem[24576];  // As 8KB | Bs 16KB
  const u16* Ab = A + (size_t)(b * RA + a0) * K;
  const u16* Bb = Bm + (size_t)(b * RB + b0) * K;
  f32x4 acc[2][4];
  #pragma unroll
  for (int i = 0; i < 2; i++)
    #pragma unroll
    for (int j = 0; j < 4; j++) acc[i][j] = (f32x4){0.f, 0.f, 0.f, 0.f};
  int K64 = K >> 6;
  for (int kt = 0; kt < K64; kt++) {
    __syncthreads();
    #pragma unroll
    for (int i = 0; i < 2; i++) {      // stage A: 64x64 bf16
      int c = tid + 256 * i;
      int row = c >> 3, col8 = c & 7;
      uint4 v = *(const uint4*)(Ab + (size_t)row * K + kt * 64 + col8 * 8);
      *(uint4*)(smem + row * 128 + ((col8 * 16) ^ ((row & 7) << 4))) = v;
    }
    #pragma unroll
    for (int i = 0; i < 4; i++) {      // stage B: 128x64 bf16
      int c = tid + 256 * i;
      int row = c >> 3, col8 = c & 7;
      uint4 v = *(const uint4*)(Bb + (size_t)row * K + kt * 64 + col8 * 8);
      *(uint4*)(smem + 8192 + row * 128 + ((col8 * 16) ^ ((row & 7) << 4))) = v;
    }
    __syncthreads();
    #pragma unroll
    for (int kk = 0; kk < 2; kk++) {
      int kbyte = kk * 64 + ((lane >> 4) << 4);
      bf16x8 af[2], bfr[4];
      #pragma unroll
      for (int i = 0; i < 2; i++) {
        int ra = wr * 32 + i * 16 + (lane & 15);
        af[i] = *(const bf16x8*)(smem + ra * 128 + (kbyte ^ ((ra & 7) << 4)));
      }
      #pragma unroll
      for (int j = 0; j < 4; j++) {
        int rb = wc * 64 + j * 16 + (lane & 15);
        bfr[j] = *(const bf16x8*)(smem + 8192 + rb * 128 + (kbyte ^ ((rb & 7) << 4)));
      }
      #pragma unroll
      for (int i = 0; i < 2; i++)
        #pragma unroll
        for (int j = 0; j < 4; j++)
          acc[i][j] = __builtin_amdgcn_mfma_f32_16x16x32_bf16(af[i], bfr[j], acc[i][j], 0, 0, 0);
    }
  }
  // epilogue: D row = a0+wr*32+i*16+(lane>>4)*4+r, col = b0+wc*64+j*16+(lane&15)
  float biasv = (EPI == 0) ? bias[0] : 0.f;
  #pragma unroll
  for (int i = 0; i < 2; i++) {
    #pragma unroll
    for (int j = 0; j < 4; j++) {
      int arow0 = a0 + wr * 32 + i * 16 + ((lane >> 4) << 2);
      int gcol = b0 + wc * 64 + j * 16 + (lane & 15);
      #pragma unroll
      for (int r = 0; r < 4; r++) {
        float v = acc[i][j][r];
        int ar = arow0 + r;
        if (EPI == 0) {
          sout[((size_t)b * L_ + ar) * M_ + gcol] =
              v + t0[b * L_ + ar] + s1m[b * M_ + gcol] + biasv;
        } else if (EPI == 1) {
          float tv = text[((size_t)b * L_ + ar) * H_ + gcol];
          size_t base = ((size_t)b * L_ + ar) * 512 + gcol;
          out[base] = tv;
          out[base + 128] = v;
          out[base + 256] = tv * v;
        } else if (EPI == 2) {
          cT[((size_t)b * H_ + ar) * M_ + gcol] = f2bf(v);
        } else {
          float tv = text[((size_t)b * L_ + ar) * H_ + gcol];
          out[((size_t)b * L_ + ar) * 512 + 384 + gcol] = tv * v;
        }
      }
    }
  }
}

// ---------------------------------------------------------------------------
// K2: row softmax over M (axis 2), masked by modality_mask. One wave per row.
// ---------------------------------------------------------------------------
__global__ __launch_bounds__(256) void row_softmax(
    const float* __restrict__ s, const int* __restrict__ mmask,
    u16* __restrict__ p1)
{
  int rg = blockIdx.x * 4 + (threadIdx.x >> 6);
  int lane = threadIdx.x & 63;
  int b = rg >> 10;
  const float* sr = s + (size_t)rg * M_;
  const int* mm = mmask + b * M_;
  float vals[16];
  float mx = -3.4e38f;
  #pragma unroll
  for (int seg = 0; seg < 4; seg++) {
    float4 v = *(const float4*)&sr[seg * 256 + lane * 4];
    int4 mk = *(const int4*)&mm[seg * 256 + lane * 4];
    vals[seg * 4 + 0] = mk.x ? v.x : NEGV;
    vals[seg * 4 + 1] = mk.y ? v.y : NEGV;
    vals[seg * 4 + 2] = mk.z ? v.z : NEGV;
    vals[seg * 4 + 3] = mk.w ? v.w : NEGV;
    mx = fmaxf(mx, fmaxf(fmaxf(vals[seg*4], vals[seg*4+1]), fmaxf(vals[seg*4+2], vals[seg*4+3])));
  }
  #pragma unroll
  for (int off = 32; off; off >>= 1) mx = fmaxf(mx, __shfl_xor(mx, off));
  float sum = 0.f;
  #pragma unroll
  for (int k = 0; k < 16; k++) { vals[k] = __expf(vals[k] - mx); sum += vals[k]; }
  #pragma unroll
  for (int off = 32; off; off >>= 1) sum += __shfl_xor(sum, off);
  float inv = 1.0f / sum;
  #pragma unroll
  for (int seg = 0; seg < 4; seg++) {
    u32 lo = (u32)f2bf(vals[seg*4+0] * inv) | ((u32)f2bf(vals[seg*4+1] * inv) << 16);
    u32 hi = (u32)f2bf(vals[seg*4+2] * inv) | ((u32)f2bf(vals[seg*4+3] * inv) << 16);
    uint2 pk; pk.x = lo; pk.y = hi;
    *(uint2*)(p1 + (size_t)rg * M_ + seg * 256 + lane * 4) = pk;
  }
}

// ---------------------------------------------------------------------------
// K3: column softmax over L (axis 1), masked by text_mask; writes p2^T (M,L)
// bf16 via LDS transpose. Block: 64 columns x full L; 4 waves split L.
// ---------------------------------------------------------------------------
__global__ __launch_bounds__(256) void col_softmax(
    const float* __restrict__ s, const int* __restrict__ tmask,
    u16* __restrict__ p2T)
{
  int b = blockIdx.y;
  int m0 = blockIdx.x * 64;
  int t = threadIdx.x, lane = t & 63, w = t >> 6;
  int m = m0 + lane;
  const float* sb = s + (size_t)b * L_ * M_;
  const int* tmb = tmask + b * L_;
  __shared__ float red[4][64];
  __shared__ u16 pt[64][66];
  // phase 1: column max
  float mx = -3.4e38f;
  for (int i = 0; i < 256; i++) {
    int l = w * 256 + i;
    float v0 = sb[(size_t)l * M_ + m];
    float v = tmb[l] ? v0 : NEGV;
    mx = fmaxf(mx, v);
  }
  red[w][lane] = mx; __syncthreads();
  mx = fmaxf(fmaxf(red[0][lane], red[1][lane]), fmaxf(red[2][lane], red[3][lane]));
  __syncthreads();
  // phase 2: column sum of exp
  float sum = 0.f;
  for (int i = 0; i < 256; i++) {
    int l = w * 256 + i;
    float v0 = sb[(size_t)l * M_ + m];
    float v = tmb[l] ? v0 : NEGV;
    sum += __expf(v - mx);
  }
  red[w][lane] = sum; __syncthreads();
  sum = red[0][lane] + red[1][lane] + red[2][lane] + red[3][lane];
  float inv = 1.0f / sum;
  __syncthreads();
  // phase 3: write p2T in 64-wide l-chunks via LDS transpose
  for (int c = 0; c < 16; c++) {
    int l0 = c * 64;
    #pragma unroll
    for (int q = 0; q < 16; q++) {
      int l = l0 + w * 16 + q;
      float v0 = sb[(size_t)l * M_ + m];
      float v = tmb[l] ? v0 : NEGV;
      pt[lane][w * 16 + q] = f2bf(__expf(v - mx) * inv);
    }
    __syncthreads();
    int lrel2 = (t & 31) * 2, mi = t >> 5;
    #pragma unroll
    for (int p = 0; p < 8; p++) {
      int mmr = mi + p * 8;
      u32 uv = *(const u32*)&pt[mmr][lrel2];
      *(u32*)&p2T[((size_t)b * M_ + m0 + mmr) * L_ + l0 + lrel2] = uv;
    }
    __syncthreads();
  }
}

// ---------------------------------------------------------------------------
extern "C" void kernel_launch(void* const* d_in, const int* in_sizes, int n_in,
                              void* d_out, int out_size, void* d_ws, size_t ws_size,
                              hipStream_t stream) {
  const float* text = (const float*)d_in[0];
  const float* modality = (const float*)d_in[1];
  const int* text_mask = (const int*)d_in[2];
  const int* modality_mask = (const int*)d_in[3];
  const float* text_weight = (const float*)d_in[4];
  const float* modality_weight = (const float*)d_in[5];
  const float* tmw = (const float*)d_in[6];
  const float* bias = (const float*)d_in[7];
  float* out = (float*)d_out;
  (void)in_sizes; (void)n_in; (void)out_size; (void)ws_size;

  char* ws = (char*)d_ws;
  size_t off = 0;
  auto alloc = [&](size_t bytes) { void* p = ws + off; off += (bytes + 255) & ~(size_t)255; return p; };
  float* s        = (float*)alloc((size_t)B_ * L_ * M_ * 4);   // 67MB
  u16*   p1       = (u16*)  alloc((size_t)B_ * L_ * M_ * 2);   // 33.5MB
  u16*   p2T      = (u16*)  alloc((size_t)B_ * M_ * L_ * 2);   // 33.5MB
  u16*   textw_bf = (u16*)  alloc((size_t)B_ * L_ * H_ * 2);   // text*tmw bf16
  u16*   mod_bf   = (u16*)  alloc((size_t)B_ * M_ * H_ * 2);
  u16*   textT_bf = (u16*)  alloc((size_t)B_ * H_ * L_ * 2);
  u16*   mod_bfT  = (u16*)  alloc((size_t)B_ * H_ * M_ * 2);
  u16*   cT       = (u16*)  alloc((size_t)B_ * H_ * M_ * 2);
  float* t0       = (float*)alloc((size_t)B_ * L_ * 4);
  float* s1m      = (float*)alloc((size_t)B_ * M_ * 4);

  prep_rows<<<4096, 256, 0, stream>>>(text, text_weight, tmw, textw_bf, t0, B_ * L_);
  prep_rows<<<4096, 256, 0, stream>>>(modality, modality_weight, nullptr, mod_bf, s1m, B_ * M_);
  transpose_bf<<<dim3(16, 2, 32), 256, 0, stream>>>(text, modality, textT_bf, mod_bfT);

  // s = textw @ mod^T + t0 + s1m + bias   (B,L,M) f32
  gemm_nt<0><<<dim3(16, 8, 16), 256, 0, stream>>>(textw_bf, mod_bf, L_, M_, H_,
      s, t0, s1m, bias, nullptr, nullptr, nullptr);
  row_softmax<<<4096, 256, 0, stream>>>(s, modality_mask, p1);
  col_softmax<<<dim3(16, 16), 256, 0, stream>>>(s, text_mask, p2T);
  // a = p1 @ modality  -> out[0:128]=text, [128:256]=a, [256:384]=text*a
  gemm_nt<1><<<dim3(16, 1, 16), 256, 0, stream>>>(p1, mod_bfT, L_, H_, M_,
      nullptr, nullptr, nullptr, nullptr, text, out, nullptr);
  // cT = text^T @ p2   (B,H,M) bf16
  gemm_nt<2><<<dim3(2, 8, 16), 256, 0, stream>>>(textT_bf, p2T, H_, M_, L_,
      nullptr, nullptr, nullptr, nullptr, nullptr, nullptr, cT);
  // b = p1 @ c -> out[384:512] = text*b
  gemm_nt<3><<<dim3(16, 1, 16), 256, 0, stream>>>(p1, cT, L_, H_, M_,
      nullptr, nullptr, nullptr, nullptr, text, out, nullptr);
}

// Round 3
// 168.373 us; speedup vs baseline: 1.5261x; 1.5261x over previous
//
#include <hip/hip_runtime.h>

#define B_ 16
#define L_ 1024
#define M_ 1024
#define H_ 128

typedef unsigned short u16;
typedef unsigned int u32;
typedef __bf16 bf16x8 __attribute__((ext_vector_type(8)));
typedef float f32x4 __attribute__((ext_vector_type(4)));

__device__ __forceinline__ u16 f2bf(float x){
  u32 u = __float_as_uint(x);
  u = (u + 0x7fffu + ((u >> 16) & 1u)) >> 16;
  return (u16)u;
}

// ---------------------------------------------------------------------------
// zero rowsum/colsum accumulators (ws is poisoned 0xAA before every launch)
// ---------------------------------------------------------------------------
__global__ __launch_bounds__(256) void zero_f32(float* __restrict__ p, int n)
{
  int i = blockIdx.x * 256 + threadIdx.x;
  if (i < n) p[i] = 0.f;
}

// ---------------------------------------------------------------------------
// prep: per-row dot (t0 / s1m, f32 exact) + bf16 pre-convert (opt * mulw).
// ---------------------------------------------------------------------------
__global__ __launch_bounds__(256) void prep_rows(
    const float* __restrict__ src, const float* __restrict__ dotw,
    const float* __restrict__ mulw, u16* __restrict__ outbf,
    float* __restrict__ dotout, int nrows)
{
  int row = blockIdx.x * 4 + (threadIdx.x >> 6);
  int lane = threadIdx.x & 63;
  if (row >= nrows) return;
  const float* r = src + (size_t)row * H_;
  float2 x = *(const float2*)&r[lane * 2];
  float2 wv = *(const float2*)&dotw[lane * 2];
  float d = x.x * wv.x + x.y * wv.y;
  #pragma unroll
  for (int off = 32; off; off >>= 1) d += __shfl_xor(d, off);
  float2 mv = mulw ? *(const float2*)&mulw[lane * 2] : make_float2(1.f, 1.f);
  u32 packed = (u32)f2bf(x.x * mv.x) | ((u32)f2bf(x.y * mv.y) << 16);
  ((u32*)outbf)[(size_t)row * 64 + lane] = packed;
  if (lane == 0) dotout[row] = d;
}

// ---------------------------------------------------------------------------
// transpose f32 (1024 x 128) -> bf16 (128 x 1024), source-row mask folded in.
// blockIdx.z: low 4 bits = batch, bit 4 = tensor select.
// ---------------------------------------------------------------------------
__global__ __launch_bounds__(256) void transpose_bf(
    const float* __restrict__ srcA, const float* __restrict__ srcB,
    const int* __restrict__ maskA, const int* __restrict__ maskB,
    u16* __restrict__ dstA, u16* __restrict__ dstB)
{
  int b = blockIdx.z & 15, sel = blockIdx.z >> 4;
  const float* src = (sel ? srcB : srcA) + (size_t)b * L_ * H_;
  const int* msk = (sel ? maskB : maskA) + b * 1024;
  u16* dst = (sel ? dstB : dstA) + (size_t)b * H_ * L_;
  int r0 = blockIdx.x * 64, h0 = blockIdx.y * 64;
  __shared__ u16 tile[64][65];
  int t = threadIdx.x;
  int j = t & 63, i0 = t >> 6;
  #pragma unroll
  for (int p = 0; p < 16; p++) {
    int i = i0 + p * 4;
    tile[i][j] = msk[r0 + i] ? f2bf(src[(size_t)(r0 + i) * H_ + h0 + j]) : (u16)0;
  }
  __syncthreads();
  int ii = (t & 15) * 4, jj0 = t >> 4;
  #pragma unroll
  for (int q = 0; q < 4; q++) {
    int jj = jj0 + q * 16;
    u32 lo = (u32)tile[ii][jj] | ((u32)tile[ii + 1][jj] << 16);
    u32 hi = (u32)tile[ii + 2][jj] | ((u32)tile[ii + 3][jj] << 16);
    uint2 pk; pk.x = lo; pk.y = hi;
    *(uint2*)&dst[(size_t)(h0 + jj) * L_ + r0 + ii] = pk;
  }
}

// ---------------------------------------------------------------------------
// gemm_exp: s = textw @ mod^T + t0 + s1m + bias; E = exp(s) (NO max-sub:
// |s| <~ 15, safe in f32/bf16). Writes E^T (M,L) bf16 via LDS repack;
// atomically accumulates masked rowsum (over m) and colsum (over l).
// Tile 64(l) x 128(m), K=128, 4 waves 2x2.
// ---------------------------------------------------------------------------
__global__ __launch_bounds__(256) void gemm_exp(
    const u16* __restrict__ A, const u16* __restrict__ Bm,
    const float* __restrict__ t0, const float* __restrict__ s1m,
    const float* __restrict__ bias, const int* __restrict__ tmask,
    const int* __restrict__ mmask, float* __restrict__ rowsum,
    float* __restrict__ colsum, u16* __restrict__ ET)
{
  int b = blockIdx.z;
  int a0 = blockIdx.x * 64, b0 = blockIdx.y * 128;
  int tid = threadIdx.x, lane = tid & 63, wid = tid >> 6;
  int wr = wid >> 1, wc = wid & 1;
  int c = lane & 15, q = lane >> 4;
  __shared__ __align__(16) char smem[24576];  // staging As|Bs; reused as E^T tile
  const u16* Ab = A + (size_t)(b * L_ + a0) * H_;
  const u16* Bb = Bm + (size_t)(b * M_ + b0) * H_;
  f32x4 acc[2][4];
  #pragma unroll
  for (int i = 0; i < 2; i++)
    #pragma unroll
    for (int j = 0; j < 4; j++) acc[i][j] = (f32x4){0.f, 0.f, 0.f, 0.f};
  for (int kt = 0; kt < 2; kt++) {
    __syncthreads();
    #pragma unroll
    for (int i = 0; i < 2; i++) {      // stage A: 64x64
      int cc = tid + 256 * i;
      int row = cc >> 3, col8 = cc & 7;
      uint4 v = *(const uint4*)(Ab + (size_t)row * H_ + kt * 64 + col8 * 8);
      *(uint4*)(smem + row * 128 + ((col8 * 16) ^ ((row & 7) << 4))) = v;
    }
    #pragma unroll
    for (int i = 0; i < 4; i++) {      // stage B: 128x64
      int cc = tid + 256 * i;
      int row = cc >> 3, col8 = cc & 7;
      uint4 v = *(const uint4*)(Bb + (size_t)row * H_ + kt * 64 + col8 * 8);
      *(uint4*)(smem + 8192 + row * 128 + ((col8 * 16) ^ ((row & 7) << 4))) = v;
    }
    __syncthreads();
    #pragma unroll
    for (int kk = 0; kk < 2; kk++) {
      int kbyte = kk * 64 + (q << 4);
      bf16x8 af[2], bfr[4];
      #pragma unroll
      for (int i = 0; i < 2; i++) {
        int ra = wr * 32 + i * 16 + c;
        af[i] = *(const bf16x8*)(smem + ra * 128 + (kbyte ^ ((ra & 7) << 4)));
      }
      #pragma unroll
      for (int j = 0; j < 4; j++) {
        int rb = wc * 64 + j * 16 + c;
        bfr[j] = *(const bf16x8*)(smem + 8192 + rb * 128 + (kbyte ^ ((rb & 7) << 4)));
      }
      #pragma unroll
      for (int i = 0; i < 2; i++)
        #pragma unroll
        for (int j = 0; j < 4; j++)
          acc[i][j] = __builtin_amdgcn_mfma_f32_16x16x32_bf16(af[i], bfr[j], acc[i][j], 0, 0, 0);
    }
  }
  // ---- epilogue: e = exp(v + t0 + s1m + bias) ----
  float biasv = bias[0];
  float t0v[2][4];
  int tmv[2][4];
  #pragma unroll
  for (int i = 0; i < 2; i++)
    #pragma unroll
    for (int r = 0; r < 4; r++) {
      int ar = a0 + wr * 32 + i * 16 + q * 4 + r;
      t0v[i][r] = t0[b * L_ + ar];
      tmv[i][r] = tmask[b * L_ + ar];
    }
  float s1v[4];
  int mmv[4];
  #pragma unroll
  for (int j = 0; j < 4; j++) {
    int gcol = b0 + wc * 64 + j * 16 + c;
    s1v[j] = s1m[b * M_ + gcol];
    mmv[j] = mmask[b * M_ + gcol];
  }
  float ev[2][4][4];
  #pragma unroll
  for (int i = 0; i < 2; i++)
    #pragma unroll
    for (int j = 0; j < 4; j++)
      #pragma unroll
      for (int r = 0; r < 4; r++)
        ev[i][j][r] = __expf(acc[i][j][r] + t0v[i][r] + s1v[j] + biasv);
  // rowsum: sum over this block's 128 m (masked), reduce over c-lanes
  #pragma unroll
  for (int i = 0; i < 2; i++)
    #pragma unroll
    for (int r = 0; r < 4; r++) {
      float prs = 0.f;
      #pragma unroll
      for (int j = 0; j < 4; j++) prs += mmv[j] ? ev[i][j][r] : 0.f;
      #pragma unroll
      for (int off = 1; off < 16; off <<= 1) prs += __shfl_xor(prs, off);
      if (c == 0) {
        int ar = a0 + wr * 32 + i * 16 + q * 4 + r;
        atomicAdd(&rowsum[b * L_ + ar], prs);
      }
    }
  // colsum: sum over this block's 64 l (masked), reduce over q-lanes
  #pragma unroll
  for (int j = 0; j < 4; j++) {
    float pcs = 0.f;
    #pragma unroll
    for (int i = 0; i < 2; i++)
      #pragma unroll
      for (int r = 0; r < 4; r++) pcs += tmv[i][r] ? ev[i][j][r] : 0.f;
    pcs += __shfl_xor(pcs, 16);
    pcs += __shfl_xor(pcs, 32);
    if (q == 0) {
      int gcol = b0 + wc * 64 + j * 16 + c;
      atomicAdd(&colsum[b * M_ + gcol], pcs);
    }
  }
  // E^T tile repack via LDS: [128 m][64 l] bf16, rows padded to 72 u16 (144B)
  __syncthreads();
  u16* et = (u16*)smem;
  #pragma unroll
  for (int i = 0; i < 2; i++)
    #pragma unroll
    for (int j = 0; j < 4; j++) {
      int gcolL = wc * 64 + j * 16 + c;
      int arL = wr * 32 + i * 16 + q * 4;
      u32 lo = (u32)f2bf(ev[i][j][0]) | ((u32)f2bf(ev[i][j][1]) << 16);
      u32 hi = (u32)f2bf(ev[i][j][2]) | ((u32)f2bf(ev[i][j][3]) << 16);
      uint2 pk; pk.x = lo; pk.y = hi;
      *(uint2*)&et[gcolL * 72 + arL] = pk;
    }
  __syncthreads();
  #pragma unroll
  for (int it = 0; it < 4; it++) {
    int mrow = (tid >> 3) + it * 32;
    int l8 = tid & 7;
    uint4 v = *(const uint4*)&et[mrow * 72 + l8 * 8];
    *(uint4*)&ET[((size_t)(b * M_ + b0 + mrow)) * L_ + a0 + l8 * 8] = v;
  }
}

// ---------------------------------------------------------------------------
// gemm_ct: cT[h][m] = (sum_l textT_m[h][l] * ET[m][l]) * mmask[m] / colsum[m].
// NT GEMM: A = textT (masked), B = E^T, K = L. Tile 64x128, bf16 out.
// ---------------------------------------------------------------------------
__global__ __launch_bounds__(256) void gemm_ct(
    const u16* __restrict__ A, const u16* __restrict__ ET,
    const int* __restrict__ mmask, const float* __restrict__ colsum,
    u16* __restrict__ cT)
{
  int b = blockIdx.z;
  int a0 = blockIdx.x * 64, b0 = blockIdx.y * 128;
  int tid = threadIdx.x, lane = tid & 63, wid = tid >> 6;
  int wr = wid >> 1, wc = wid & 1;
  int c = lane & 15, q = lane >> 4;
  __shared__ __align__(16) char smem[24576];
  const u16* Ab = A + (size_t)(b * H_ + a0) * L_;
  const u16* Bb = ET + (size_t)(b * M_ + b0) * L_;
  f32x4 acc[2][4];
  #pragma unroll
  for (int i = 0; i < 2; i++)
    #pragma unroll
    for (int j = 0; j < 4; j++) acc[i][j] = (f32x4){0.f, 0.f, 0.f, 0.f};
  for (int kt = 0; kt < 16; kt++) {
    __syncthreads();
    #pragma unroll
    for (int i = 0; i < 2; i++) {
      int cc = tid + 256 * i;
      int row = cc >> 3, col8 = cc & 7;
      uint4 v = *(const uint4*)(Ab + (size_t)row * L_ + kt * 64 + col8 * 8);
      *(uint4*)(smem + row * 128 + ((col8 * 16) ^ ((row & 7) << 4))) = v;
    }
    #pragma unroll
    for (int i = 0; i < 4; i++) {
      int cc = tid + 256 * i;
      int row = cc >> 3, col8 = cc & 7;
      uint4 v = *(const uint4*)(Bb + (size_t)row * L_ + kt * 64 + col8 * 8);
      *(uint4*)(smem + 8192 + row * 128 + ((col8 * 16) ^ ((row & 7) << 4))) = v;
    }
    __syncthreads();
    #pragma unroll
    for (int kk = 0; kk < 2; kk++) {
      int kbyte = kk * 64 + (q << 4);
      bf16x8 af[2], bfr[4];
      #pragma unroll
      for (int i = 0; i < 2; i++) {
        int ra = wr * 32 + i * 16 + c;
        af[i] = *(const bf16x8*)(smem + ra * 128 + (kbyte ^ ((ra & 7) << 4)));
      }
      #pragma unroll
      for (int j = 0; j < 4; j++) {
        int rb = wc * 64 + j * 16 + c;
        bfr[j] = *(const bf16x8*)(smem + 8192 + rb * 128 + (kbyte ^ ((rb & 7) << 4)));
      }
      #pragma unroll
      for (int i = 0; i < 2; i++)
        #pragma unroll
        for (int j = 0; j < 4; j++)
          acc[i][j] = __builtin_amdgcn_mfma_f32_16x16x32_bf16(af[i], bfr[j], acc[i][j], 0, 0, 0);
    }
  }
  float invc[4];
  #pragma unroll
  for (int j = 0; j < 4; j++) {
    int gcol = b0 + wc * 64 + j * 16 + c;
    int mm = mmask[b * M_ + gcol];
    invc[j] = mm ? 1.0f / fmaxf(colsum[b * M_ + gcol], 1e-30f) : 0.f;
  }
  #pragma unroll
  for (int i = 0; i < 2; i++)
    #pragma unroll
    for (int j = 0; j < 4; j++) {
      int arow0 = a0 + wr * 32 + i * 16 + q * 4;
      int gcol = b0 + wc * 64 + j * 16 + c;
      #pragma unroll
      for (int r = 0; r < 4; r++)
        cT[((size_t)(b * H_ + arow0 + r)) * M_ + gcol] = f2bf(acc[i][j][r] * invc[j]);
    }
}

// ---------------------------------------------------------------------------
// gemm_ab: a = (E @ mod_mT^T)/rowsum, bb = (E @ cT^T)/rowsum, K = M.
// A-tiles staged from E^T via padded LDS transpose (scalar u16 frag reads).
// Writes out[text | a | text*a | text*bb].
// ---------------------------------------------------------------------------
__global__ __launch_bounds__(256) void gemm_ab(
    const u16* __restrict__ ET, const u16* __restrict__ B1,
    const u16* __restrict__ B2, const float* __restrict__ rowsum,
    const float* __restrict__ text, float* __restrict__ out)
{
  int b = blockIdx.z;
  int a0 = blockIdx.x * 64;
  int tid = threadIdx.x, lane = tid & 63, wid = tid >> 6;
  int wr = wid >> 1, wc = wid & 1;
  int c = lane & 15, q = lane >> 4;
  __shared__ __align__(16) u16 At[64 * 76];       // [m 64][l 64] pad 76
  __shared__ __align__(16) char Bs[2][16384];
  const u16* ETb = ET + (size_t)b * M_ * L_;
  const u16* B1b = B1 + (size_t)b * H_ * M_;
  const u16* B2b = B2 + (size_t)b * H_ * M_;
  f32x4 acc_a[2][4], acc_b[2][4];
  #pragma unroll
  for (int i = 0; i < 2; i++)
    #pragma unroll
    for (int j = 0; j < 4; j++) {
      acc_a[i][j] = (f32x4){0.f, 0.f, 0.f, 0.f};
      acc_b[i][j] = (f32x4){0.f, 0.f, 0.f, 0.f};
    }
  for (int kt = 0; kt < 16; kt++) {
    __syncthreads();
    // stage A (64 l x 64 m) from E^T rows [kt*64, kt*64+64), cols [a0, a0+64)
    #pragma unroll
    for (int it = 0; it < 2; it++) {
      int mloc = (tid >> 3) + it * 32;
      int l8 = tid & 7;
      uint4 v = *(const uint4*)&ETb[((size_t)(kt * 64 + mloc)) * L_ + a0 + l8 * 8];
      u16* rp = At + mloc * 76 + l8 * 8;
      uint2 p0; p0.x = v.x; p0.y = v.y;
      uint2 p1; p1.x = v.z; p1.y = v.w;
      *(uint2*)rp = p0;
      *(uint2*)(rp + 4) = p1;
    }
    // stage B1, B2 (128 h x 64 m), XOR-swizzled
    #pragma unroll
    for (int i = 0; i < 4; i++) {
      int cc = tid + 256 * i;
      int row = cc >> 3, col8 = cc & 7;
      uint4 v1 = *(const uint4*)(B1b + (size_t)row * M_ + kt * 64 + col8 * 8);
      *(uint4*)(Bs[0] + row * 128 + ((col8 * 16) ^ ((row & 7) << 4))) = v1;
      uint4 v2 = *(const uint4*)(B2b + (size_t)row * M_ + kt * 64 + col8 * 8);
      *(uint4*)(Bs[1] + row * 128 + ((col8 * 16) ^ ((row & 7) << 4))) = v2;
    }
    __syncthreads();
    #pragma unroll
    for (int kk = 0; kk < 2; kk++) {
      int kbyte = kk * 64 + (q << 4);
      bf16x8 af[2], b1f[4], b2f[4];
      #pragma unroll
      for (int i = 0; i < 2; i++) {
        int lidx = wr * 32 + i * 16 + c;
        int mbase = kk * 32 + q * 8;
        union { unsigned short s[8]; bf16x8 v; } ua;
        #pragma unroll
        for (int e = 0; e < 8; e++) ua.s[e] = At[(mbase + e) * 76 + lidx];
        af[i] = ua.v;
      }
      #pragma unroll
      for (int j = 0; j < 4; j++) {
        int rb = wc * 64 + j * 16 + c;
        b1f[j] = *(const bf16x8*)(Bs[0] + rb * 128 + (kbyte ^ ((rb & 7) << 4)));
        b2f[j] = *(const bf16x8*)(Bs[1] + rb * 128 + (kbyte ^ ((rb & 7) << 4)));
      }
      #pragma unroll
      for (int i = 0; i < 2; i++)
        #pragma unroll
        for (int j = 0; j < 4; j++) {
          acc_a[i][j] = __builtin_amdgcn_mfma_f32_16x16x32_bf16(af[i], b1f[j], acc_a[i][j], 0, 0, 0);
          acc_b[i][j] = __builtin_amdgcn_mfma_f32_16x16x32_bf16(af[i], b2f[j], acc_b[i][j], 0, 0, 0);
        }
    }
  }
  float irs[2][4];
  #pragma unroll
  for (int i = 0; i < 2; i++)
    #pragma unroll
    for (int r = 0; r < 4; r++) {
      int ar = a0 + wr * 32 + i * 16 + q * 4 + r;
      irs[i][r] = 1.0f / fmaxf(rowsum[b * L_ + ar], 1e-30f);
    }
  #pragma unroll
  for (int i = 0; i < 2; i++)
    #pragma unroll
    for (int j = 0; j < 4; j++) {
      int gcol = wc * 64 + j * 16 + c;
      #pragma unroll
      for (int r = 0; r < 4; r++) {
        int ar = a0 + wr * 32 + i * 16 + q * 4 + r;
        float av = acc_a[i][j][r] * irs[i][r];
        float bv = acc_b[i][j][r] * irs[i][r];
        float tv = text[((size_t)(b * L_ + ar)) * H_ + gcol];
        size_t base = ((size_t)(b * L_ + ar)) * 512 + gcol;
        out[base] = tv;
        out[base + 128] = av;
        out[base + 256] = tv * av;
        out[base + 384] = tv * bv;
      }
    }
}

// ---------------------------------------------------------------------------
extern "C" void kernel_launch(void* const* d_in, const int* in_sizes, int n_in,
                              void* d_out, int out_size, void* d_ws, size_t ws_size,
                              hipStream_t stream) {
  const float* text = (const float*)d_in[0];
  const float* modality = (const float*)d_in[1];
  const int* text_mask = (const int*)d_in[2];
  const int* modality_mask = (const int*)d_in[3];
  const float* text_weight = (const float*)d_in[4];
  const float* modality_weight = (const float*)d_in[5];
  const float* tmw = (const float*)d_in[6];
  const float* bias = (const float*)d_in[7];
  float* out = (float*)d_out;
  (void)in_sizes; (void)n_in; (void)out_size; (void)ws_size;

  char* ws = (char*)d_ws;
  size_t off = 0;
  auto alloc = [&](size_t bytes) { void* p = ws + off; off += (bytes + 255) & ~(size_t)255; return p; };
  u16*   ET       = (u16*)  alloc((size_t)B_ * M_ * L_ * 2);   // 33.5MB
  u16*   textw_bf = (u16*)  alloc((size_t)B_ * L_ * H_ * 2);
  u16*   mod_bf   = (u16*)  alloc((size_t)B_ * M_ * H_ * 2);
  u16*   textT_bf = (u16*)  alloc((size_t)B_ * H_ * L_ * 2);   // masked by tmask
  u16*   mod_bfT  = (u16*)  alloc((size_t)B_ * H_ * M_ * 2);   // masked by mmask
  u16*   cT       = (u16*)  alloc((size_t)B_ * H_ * M_ * 2);
  float* t0       = (float*)alloc((size_t)B_ * L_ * 4);
  float* s1m      = (float*)alloc((size_t)B_ * M_ * 4);
  float* rowsum   = (float*)alloc((size_t)B_ * L_ * 4);
  float* colsum   = (float*)alloc((size_t)B_ * M_ * 4);

  zero_f32<<<128, 256, 0, stream>>>(rowsum, B_ * (L_ + M_));  // rowsum+colsum contiguous
  prep_rows<<<4096, 256, 0, stream>>>(text, text_weight, tmw, textw_bf, t0, B_ * L_);
  prep_rows<<<4096, 256, 0, stream>>>(modality, modality_weight, nullptr, mod_bf, s1m, B_ * M_);
  transpose_bf<<<dim3(16, 2, 32), 256, 0, stream>>>(text, modality, text_mask, modality_mask,
                                                    textT_bf, mod_bfT);
  gemm_exp<<<dim3(16, 8, 16), 256, 0, stream>>>(textw_bf, mod_bf, t0, s1m, bias,
      text_mask, modality_mask, rowsum, colsum, ET);
  gemm_ct<<<dim3(2, 8, 16), 256, 0, stream>>>(textT_bf, ET, modality_mask, colsum, cT);
  gemm_ab<<<dim3(16, 1, 16), 256, 0, stream>>>(ET, mod_bfT, cT, rowsum, text, out);
}